// Round 14
// baseline (425.338 us; speedup 1.0000x reference)
//
#include <hip/hip_runtime.h>
#include <hip/hip_bf16.h>
#include <stdint.h>

typedef __hip_bfloat16 bf16;

using sh8    = __attribute__((ext_vector_type(8)))  short;
using sh4    = __attribute__((ext_vector_type(4)))  short;
using us4    = __attribute__((ext_vector_type(4)))  unsigned short;
using f32x16 = __attribute__((ext_vector_type(16))) float;
using fx4    = __attribute__((ext_vector_type(4)))  float;

#define NN    4096
#define NODES 8192
#define DIM   128
#define MD    16
#define KNNK  32
#define H1N   530
#define CPAD  544      // H1N padded to 17*32
#define PROW  1088     // [Pi 544 | Pj 544] per node, bf16

// weight-image offsets (in shorts)
#define OFF_W1AB 0      // [2][544][8]: half0 = W1f rows f0..7; half1 = [W1f8,0..0]
#define OFF_WE2A 8704   // [o][c] s=552  8832
#define OFF_WC1A 17536  // [u][k] s=32   2048
#define OFF_BE2  19584  // fp32[16]        32
#define OFF_BC1  19616  // fp32[64]       128
#define OFF_WC2  19744  // fp32[64]       128
#define OFF_BC2  19872  // fp32[4]          8
#define WIMG_SH  19880

__device__ __forceinline__ float b2f(bf16 x){ return __bfloat162float(x); }
__device__ __forceinline__ bf16  f2b(float x){ return __float2bfloat16(x); }
// fast silu: v_rcp_f32 (~1 ulp) instead of IEEE division
__device__ __forceinline__ float silu_f(float x){
    return x * __builtin_amdgcn_rcpf(1.f + __expf(-x));
}

__device__ __forceinline__ unsigned short f2us(float f){
    unsigned x = __float_as_uint(f);
    unsigned r = x + 0x7FFFu + ((x >> 16) & 1u);
    return (unsigned short)(r >> 16);
}
__device__ __forceinline__ float us2f(unsigned short u){
    return __uint_as_float(((unsigned)u) << 16);
}
// packed fp32x2 -> bf16x2 (v_cvt_pk_bf16_f32 on gfx950); low short = a
__device__ __forceinline__ unsigned pkbf(float a, float b){
    __hip_bfloat162 v = __float22bfloat162_rn(make_float2(a, b));
    return *(unsigned*)&v;
}

// ---------------------------------------------------------------- K0: dtype detect
struct Ptrs { const void* p[14]; int n[14]; };

__global__ __launch_bounds__(256) void detect_kernel(Ptrs ps, int* flags){
    int tn = blockIdx.x;
    const bf16* s = (const bf16*)ps.p[tn];
    int n = ps.n[tn]; if (n > 8192) n = 8192;
    int bad = 0;
    for (int i = threadIdx.x; i < n; i += 256){
        float v = b2f(s[i]);
        if (!(fabsf(v) <= 64.f)) bad = 1;   // catches NaN/Inf too
    }
    __shared__ int sbad;
    if (threadIdx.x == 0) sbad = 0;
    __syncthreads();
    if (bad) atomicOr(&sbad, 1);
    __syncthreads();
    if (threadIdx.x == 0) flags[tn] = sbad;   // 1 = fp32, 0 = bf16
}

// ---------------------------------------------------------------- K0b: fused convert
struct ConvTab {
    const void* src[14];
    int dstoff[14];
    int prefix[15];
};

__global__ __launch_bounds__(256) void convert_all(ConvTab tab,
                                                   const int* __restrict__ flags,
                                                   float* __restrict__ base){
    int gid = blockIdx.x * 256 + threadIdx.x;
    if (gid >= tab.prefix[14]) return;
    int tn = 0;
    #pragma unroll
    for (int k = 1; k < 14; ++k)
        if (gid >= tab.prefix[k]) tn = k;
    int local = gid - tab.prefix[tn];
    int f = flags[tn];
    float v = f ? ((const float*)tab.src[tn])[local]
                : b2f(((const bf16*)tab.src[tn])[local]);
    base[tab.dstoff[tn] + local] = v;
}

// ---------------------------------------------------------------- K0c: weight prep
__global__ __launch_bounds__(256) void prep_kernel(
        const float* __restrict__ We1, const float* __restrict__ We2,
        const float* __restrict__ Wc1, const float* __restrict__ be2,
        const float* __restrict__ bc1, const float* __restrict__ Wc2,
        const float* __restrict__ bc2, const float* __restrict__ feats,
        unsigned short* __restrict__ gwimg,
        unsigned short* __restrict__ We1T,
        unsigned short* __restrict__ fBF){
    int gid = blockIdx.x * 256 + threadIdx.x;
    if (gid < 4352){                         // W1AB half0: [c][f0..7]
        int c = gid >> 3, f = gid & 7;
        gwimg[OFF_W1AB + gid] = (c < H1N) ? f2us(We1[(size_t)(256 + f) * H1N + c]) : 0;
    } else if (gid < 8704){                  // W1AB half1: [c][W1f8,0,...]
        int e = gid - 4352; int c = e >> 3, jj = e & 7;
        gwimg[OFF_W1AB + 4352 + e] =
            (jj == 0 && c < H1N) ? f2us(We1[(size_t)264 * H1N + c]) : 0;
    } else if (gid < 17536){                 // We2^T s=552
        int e = gid - 8704; int o = e / 552, c = e - o * 552;
        gwimg[OFF_WE2A + e] = (c < H1N) ? f2us(We2[(size_t)c * 16 + o]) : 0;
    } else if (gid < 19584){                 // Wc1^T s=32
        int e = gid - 17536; int u = e >> 5, k = e & 31;
        gwimg[OFF_WC1A + e] = (k < 16) ? f2us(Wc1[(size_t)k * 64 + u]) : 0;
    } else if (gid < 19600){
        ((float*)(gwimg + OFF_BE2))[gid - 19584] = be2[gid - 19584];
    } else if (gid < 19664){
        ((float*)(gwimg + OFF_BC1))[gid - 19600] = bc1[gid - 19600];
    } else if (gid < 19728){
        ((float*)(gwimg + OFF_WC2))[gid - 19664] = Wc2[gid - 19664];
    } else if (gid < 19732){
        int z = gid - 19728;
        ((float*)(gwimg + OFF_BC2))[z] = (z == 0) ? bc2[0] : 0.f;
    } else if (gid >= 32768 && gid < 32768 + 1088 * 128){
        int e = gid - 32768; int n = e >> 7, k = e & 127;
        float v;
        if (n < CPAD) v = (n < H1N) ? We1[(size_t)k * H1N + n] : 0.f;
        else { int n2 = n - CPAD; v = (n2 < H1N) ? We1[(size_t)(128 + k) * H1N + n2] : 0.f; }
        We1T[e] = f2us(v);
    } else if (gid >= 172032 && gid < 172032 + NODES * DIM){
        int e = gid - 172032;
        fBF[e] = f2us(feats[e]);
    }
}

// ---------------------------------------------------------------- K1: KNN — wave-autonomous radix select
// One WAVE per node (8 nodes / 512-thr block, grid 1024 = 4 blocks/CU).
// Zero __syncthreads: per-wave private 1024-bin LDS histogram, intra-wave
// shfl scan, wave-local atomic emit, boundary bin resolved exactly via a
// 64-entry (d_bits,j) u64 list + shfl-min rounds (full-rescan fallback if
// the bin overflows the list). Set identical to jax.lax.top_k(-d, 32).
__global__ __launch_bounds__(512, 6) void knn_kernel(const float* __restrict__ coors,
                                                     int* __restrict__ idx_out){
    __shared__ unsigned hist[8][1024];              // 32 KB, wave-private
    __shared__ unsigned long long blist[8][64];     //  4 KB, wave-private
    __shared__ int cntO[8], cntB[8];

    int t = threadIdx.x, lane = t & 63, wid = t >> 6;
    int node = (blockIdx.x << 3) + wid;
    int b = node >> 12, i = node & (NN - 1);
    const float* cb = coors + (size_t)b * NN * 3;

    float qx = cb[i*3+0], qy = cb[i*3+1], qz = cb[i*3+2];

    unsigned* h = &hist[wid][0];
    // zero private hist: 4 x uint4 per lane (1024 bins)
    {
        uint4* hz = (uint4*)h;
        uint4 z = make_uint4(0,0,0,0);
        #pragma unroll
        for (int zl = 0; zl < 4; ++zl) hz[zl * 64 + lane] = z;
    }
    if (lane == 0){ cntO[wid] = 0; cntB[wid] = 0; }
    asm volatile("" ::: "memory");

    // pass 1: distances, bucket cache (packed 2x16b), histogram
    unsigned bkp[32];
    #pragma unroll
    for (int so = 0; so < 8; ++so){
        #pragma unroll
        for (int si = 0; si < 8; ++si){
            int s = so * 8 + si;
            int j = (s << 6) + lane;
            float dx = qx - cb[j*3+0];
            float dy = qy - cb[j*3+1];
            float dz = qz - cb[j*3+2];
            float d  = dx*dx + dy*dy + dz*dz;
            float d2 = d * d;
            unsigned bk = __float_as_uint(d2 * d2) >> 22;
            if ((s & 1) == 0) bkp[s >> 1] = bk;
            else              bkp[s >> 1] |= bk << 16;
            atomicAdd(&h[bk], 1u);
        }
        asm volatile("" ::: "memory");   // cap load clustering (VGPR)
    }
    asm volatile("s_waitcnt lgkmcnt(0)" ::: "memory");

    // intra-wave scan: lane owns bins [lane*16, lane*16+16)
    unsigned c16[16];
    {
        uint4* hz = (uint4*)h;
        #pragma unroll
        for (int g = 0; g < 4; ++g){
            uint4 v = hz[lane * 4 + g];
            c16[g*4+0] = v.x; c16[g*4+1] = v.y; c16[g*4+2] = v.z; c16[g*4+3] = v.w;
        }
    }
    unsigned S = 0;
    #pragma unroll
    for (int r = 0; r < 16; ++r) S += c16[r];
    unsigned scan = S;
    #pragma unroll
    for (int off = 1; off < 64; off <<= 1){
        unsigned nv = __shfl_up(scan, off);
        if (lane >= off) scan += nv;
    }
    unsigned excl = scan - S;
    unsigned long long own = __ballot(excl < KNNK && excl + S >= KNNK);
    int src = __ffsll((unsigned long long)own) - 1;
    unsigned run = excl, Bloc = 0, below_l = 0;
    #pragma unroll
    for (int r = 0; r < 16; ++r){
        if (run < KNNK && run + c16[r] >= KNNK){ Bloc = lane * 16 + r; below_l = run; }
        run += c16[r];
    }
    unsigned B    = __shfl(Bloc, src);
    unsigned below= __shfl(below_l, src);
    unsigned need = KNNK - below;

    // pass 2: emit strictly-below; push boundary (d recomputed, few lanes)
    int* co = &cntO[wid];
    int* cbn = &cntB[wid];
    unsigned long long* bl = &blist[wid][0];
    #pragma unroll
    for (int s = 0; s < 64; ++s){
        unsigned bk = (bkp[s >> 1] >> ((s & 1) * 16)) & 0xffffu;
        int j = (s << 6) + lane;
        if (bk < B){
            int pos = atomicAdd(co, 1);
            idx_out[(size_t)node * KNNK + pos] = j;
        } else if (bk == B){
            float dx = qx - cb[j*3+0];
            float dy = qy - cb[j*3+1];
            float dz = qz - cb[j*3+2];
            float d  = dx*dx + dy*dy + dz*dz;
            unsigned long long mk = ((unsigned long long)__float_as_uint(d) << 32)
                                    | (unsigned)j;
            int p = atomicAdd(cbn, 1);
            if (p < 64) bl[p] = mk;
        }
    }
    asm volatile("s_waitcnt lgkmcnt(0) vmcnt(0)" ::: "memory");
    int nb = *cbn;   // same-wave LDS in-order

    if (nb <= 64){
        // selection over the list: need rounds of wave-min
        unsigned long long e = (lane < nb) ? bl[lane] : ~0ull;
        for (unsigned r = 0; r < need; ++r){
            unsigned long long m = e;
            #pragma unroll
            for (int off = 32; off > 0; off >>= 1){
                unsigned long long o = __shfl_xor(m, off);
                if (o < m) m = o;
            }
            if (lane == 0)
                idx_out[(size_t)node * KNNK + below + r] = (int)(unsigned)(m & 0xffffffffull);
            if (e == m) e = ~0ull;
        }
    } else {
        // ~never: boundary bin overflowed the list — exact full-rescan selection
        unsigned long long lastk = 0;
        for (unsigned r = 0; r < need; ++r){
            unsigned long long lmin = ~0ull;
            for (int s = 0; s < 64; ++s){
                int j = (s << 6) + lane;
                float dx = qx - cb[j*3+0];
                float dy = qy - cb[j*3+1];
                float dz = qz - cb[j*3+2];
                float d  = dx*dx + dy*dy + dz*dz;
                float d2 = d * d;
                if ((__float_as_uint(d2 * d2) >> 22) == B){
                    unsigned long long mk = (((unsigned long long)__float_as_uint(d) << 32)
                                             | (unsigned)j) + 1ull;
                    if (mk > lastk && mk < lmin) lmin = mk;
                }
            }
            #pragma unroll
            for (int off = 32; off > 0; off >>= 1){
                unsigned long long o = __shfl_xor(lmin, off);
                if (o < lmin) lmin = o;
            }
            if (lane == 0)
                idx_out[(size_t)node * KNNK + below + r] =
                    (int)(unsigned)((lmin - 1ull) & 0xffffffffull);
            lastk = lmin;
        }
    }
}

// ---------------------------------------------------------------- K2: P-GEMM (MFMA, both batches)
__global__ __launch_bounds__(256) void p_gemm(const unsigned short* __restrict__ fBF,
                                              const unsigned short* __restrict__ We1T,
                                              const float* __restrict__ be1,
                                              unsigned short* __restrict__ P){
    int t = threadIdx.x, lane = t & 63, wid = t >> 6;
    int e31 = lane & 31, hi = lane >> 5;
    int mW = (blockIdx.x << 7) + (wid << 5);
    int n0 = blockIdx.y << 5;

    const unsigned short* Arow = fBF  + (size_t)(mW + e31) * DIM + hi * 8;
    const unsigned short* Brow = We1T + (size_t)(n0 + e31) * DIM + hi * 8;

    f32x16 acc = {0.f,0.f,0.f,0.f,0.f,0.f,0.f,0.f,0.f,0.f,0.f,0.f,0.f,0.f,0.f,0.f};
    #pragma unroll
    for (int kc = 0; kc < 8; ++kc){
        sh8 a  = *(const sh8*)(Arow + kc * 16);
        sh8 bv = *(const sh8*)(Brow + kc * 16);
        acc = __builtin_amdgcn_mfma_f32_32x32x16_bf16(a, bv, acc, 0, 0, 0);
    }
    int n = n0 + e31;
    float beadd = 0.f;
    if (n < CPAD) beadd = (n < H1N) ? be1[n] : 0.f;   // fold be1 into Pi half
    #pragma unroll
    for (int g = 0; g < 4; ++g)
        #pragma unroll
        for (int r = 0; r < 4; ++r){
            int m = mW + 8*g + 4*hi + r;
            P[(size_t)m * PROW + n] = f2us(acc[4*g + r] + beadd);
        }
}

// ---------------------------------------------------------------- K3: edges (MFMA, 8 nodes/block)
// 512 threads = 8 waves, 1 wave/node. Pj stream coalesced via wave-local LDS
// stage (2 whole-line loads/lane per chunk). See R13 notes.
__global__ __launch_bounds__(512, 6) void edge_kernel(
        const float* __restrict__ coors, const int* __restrict__ idx,
        const unsigned short* __restrict__ gw,
        const unsigned short* __restrict__ P,
        float* __restrict__ mi_out, void* __restrict__ dout,
        const int* __restrict__ flagp){
    __shared__ __align__(16) unsigned short sWe2[16 * 552];   // 17.7 KB
    __shared__ __align__(16) unsigned short trans[8][1280];   // 20.5 KB (wave-local)

    int t = threadIdx.x, lane = t & 63, wid = t >> 6;
    int gnode = (blockIdx.x << 3) + wid;
    int b = gnode >> 12;

    {   // stage We2^T (coalesced float4 copy), one barrier
        const float4* s1 = (const float4*)(gw + OFF_WE2A);
        float4* d1 = (float4*)sWe2;
        for (int e = t; e < 1104; e += 512) d1[e] = s1[e];
    }

    const float* cb = coors + (size_t)b * NN * 3;
    int i = gnode & (NN - 1);
    float qx = cb[i*3+0], qy = cb[i*3+1], qz = cb[i*3+2];

    int e31 = lane & 31, hi = lane >> 5;
    int e15 = lane & 15, q  = lane >> 4;

    // every lane owns edge e31 (lanes 32..63 duplicate 0..31)
    int jme = idx[(size_t)gnode * KNNK + e31];
    float rx = qx - cb[jme*3+0];
    float ry = qy - cb[jme*3+1];
    float rz = qz - cb[jme*3+2];
    float d = rx*rx + ry*ry + rz*rz;

    unsigned frb[9];
    frb[0] = f2us(sinf(d));         frb[1] = f2us(sinf(d * 0.5f));
    frb[2] = f2us(sinf(d * 0.25f)); frb[3] = f2us(sinf(d * 0.125f));
    frb[4] = f2us(cosf(d));         frb[5] = f2us(cosf(d * 0.5f));
    frb[6] = f2us(cosf(d * 0.25f)); frb[7] = f2us(cosf(d * 0.125f));
    frb[8] = f2us(d);

    // hi=0: B[k=0..7][e] = fourier; hi=1: B[8][e]=d, B[9][e]=1.0 (Pi slot)
    sh8 bfragC;
    #pragma unroll
    for (int j = 0; j < 8; ++j)
        bfragC[j] = (hi == 0) ? (short)frb[j]
                  : (short)((j == 0) ? frb[8] : (j == 1) ? 0x3F80u : 0u);

    // coalesced Pj staging: lane covers row (lane>>2) and row 16+(lane>>2),
    // 16 B each at quarter (lane&3). Whole 64 B lines per row.
    int nbase = gnode & ~(NN - 1);
    int j0 = __shfl(jme, lane >> 2);
    int j1 = __shfl(jme, 16 + (lane >> 2));
    const unsigned short* Pst0 = P + (size_t)(nbase + j0) * PROW + CPAD + (lane & 3) * 8;
    const unsigned short* Pst1 = P + (size_t)(nbase + j1) * PROW + CPAD + (lane & 3) * 8;
    const unsigned short* Pirow = P + (size_t)gnode * PROW;

    unsigned short* stg = &trans[wid][0];                 // stride 40 shorts
    unsigned short* sw0 = stg + (lane >> 2) * 40 + (lane & 3) * 8;
    unsigned short* sw1 = stg + (16 + (lane >> 2)) * 40 + (lane & 3) * 8;

    const float* g_be2 = (const float*)(gw + OFF_BE2);
    const float* g_bc1 = (const float*)(gw + OFF_BC1);
    const float* g_wc2 = (const float*)(gw + OFF_WC2);
    const float* g_bc2 = (const float*)(gw + OFF_BC2);

    fx4 accD0 = {0.f,0.f,0.f,0.f};
    fx4 accD1 = {0.f,0.f,0.f,0.f};

    __syncthreads();   // staged weights visible

    for (int ch = 0; ch < 17; ++ch){
        int c0 = ch * 32;
        // coalesced Pj stage: 2 x 16 B/lane -> 32 rows x 64 B
        sh8 g0v = *(const sh8*)(Pst0 + c0);
        sh8 g1v = *(const sh8*)(Pst1 + c0);
        unsigned short piS = Pirow[c0 + e31];
        sh8 afrag = *(const sh8*)(gw + OFF_W1AB + (size_t)(hi * 544 + c0 + e31) * 8);
        afrag[1] = hi ? (short)piS : afrag[1];            // Pi into k=9 slot

        *(sh8*)sw0 = g0v;                                  // ds_write_b128 x2
        *(sh8*)sw1 = g1v;
        asm volatile("s_waitcnt lgkmcnt(0)" ::: "memory"); // stage visible (intra-wave)

        f32x16 cc;   // C-init = Pj (from LDS stage); Pi comes through the MFMA
        #pragma unroll
        for (int g = 0; g < 4; ++g){
            us4 pj = *(const us4*)(stg + e31 * 40 + 8*g + 4*hi);
            cc[4*g+0] = us2f(pj.x);
            cc[4*g+1] = us2f(pj.y);
            cc[4*g+2] = us2f(pj.z);
            cc[4*g+3] = us2f(pj.w);
        }
        f32x16 h = __builtin_amdgcn_mfma_f32_32x32x16_bf16(afrag, bfragC, cc, 0, 0, 0);

        // h1 -> bf16 into the SAME buffer (Pj values already consumed;
        // same-wave LDS ops process in order)
        #pragma unroll
        for (int g = 0; g < 4; ++g){
            unsigned lo = pkbf(silu_f(h[4*g+0]), silu_f(h[4*g+1]));
            unsigned hi2 = pkbf(silu_f(h[4*g+2]), silu_f(h[4*g+3]));
            *(uint2*)&stg[e31 * 40 + 8*g + 4*hi] = make_uint2(lo, hi2);
        }
        asm volatile("s_waitcnt lgkmcnt(0)" ::: "memory"); // intra-wave LDS RAW

        sh8 wa  = *(const sh8*)&sWe2[e15 * 552 + c0 + q * 8];
        sh8 bt0 = *(const sh8*)&stg[e15 * 40 + q * 8];
        sh8 bt1 = *(const sh8*)&stg[(16 + e15) * 40 + q * 8];
        accD0 = __builtin_amdgcn_mfma_f32_16x16x32_bf16(wa, bt0, accD0, 0, 0, 0);
        accD1 = __builtin_amdgcn_mfma_f32_16x16x32_bf16(wa, bt1, accD1, 0, 0, 0);
    }

    // ---- m = silu(OUT2 + be2); sM (aliases trans head); m_i butterfly ----
    fx4 be2q = *(const fx4*)&g_be2[q * 4];
    float msum[4];
    float mv0[4], mv1[4];
    #pragma unroll
    for (int r = 0; r < 4; ++r){
        mv0[r] = silu_f(accD0[r] + be2q[r]);
        mv1[r] = silu_f(accD1[r] + be2q[r]);
        msum[r] = mv0[r] + mv1[r];
    }
    *(uint2*)&stg[e15 * 16 + q * 4] =
        make_uint2(pkbf(mv0[0], mv0[1]), pkbf(mv0[2], mv0[3]));
    *(uint2*)&stg[(16 + e15) * 16 + q * 4] =
        make_uint2(pkbf(mv1[0], mv1[1]), pkbf(mv1[2], mv1[3]));
    #pragma unroll
    for (int r = 0; r < 4; ++r){
        msum[r] += __shfl_xor(msum[r], 1);
        msum[r] += __shfl_xor(msum[r], 2);
        msum[r] += __shfl_xor(msum[r], 4);
        msum[r] += __shfl_xor(msum[r], 8);
    }
    if (e15 == 0){
        fx4 mv = { msum[0], msum[1], msum[2], msum[3] };
        *(fx4*)(mi_out + (size_t)gnode * MD + q * 4) = mv;
    }
    asm volatile("s_waitcnt lgkmcnt(0)" ::: "memory");

    // ---- phase E: coors MLP ----
    float tsum0 = 0.f, tsum1 = 0.f;
    #pragma unroll
    for (int ut = 0; ut < 4; ++ut){
        sh8 wa3 = *(const sh8*)(gw + OFF_WC1A + (size_t)(ut * 16 + e15) * 32 + q * 8);
        sh8 b0  = (q < 2) ? *(const sh8*)&stg[e15 * 16 + q * 8]        : (sh8)0;
        sh8 b1  = (q < 2) ? *(const sh8*)&stg[(16 + e15) * 16 + q * 8] : (sh8)0;
        fx4 a0 = {0.f,0.f,0.f,0.f};
        fx4 a1 = {0.f,0.f,0.f,0.f};
        a0 = __builtin_amdgcn_mfma_f32_16x16x32_bf16(wa3, b0, a0, 0, 0, 0);
        a1 = __builtin_amdgcn_mfma_f32_16x16x32_bf16(wa3, b1, a1, 0, 0, 0);
        fx4 bc1q = *(const fx4*)&g_bc1[ut * 16 + q * 4];
        fx4 wcq  = *(const fx4*)&g_wc2[ut * 16 + q * 4];
        #pragma unroll
        for (int r = 0; r < 4; ++r){
            tsum0 += silu_f(a0[r] + bc1q[r]) * wcq[r];
            tsum1 += silu_f(a1[r] + bc1q[r]) * wcq[r];
        }
    }
    tsum0 += __shfl_xor(tsum0, 16); tsum0 += __shfl_xor(tsum0, 32);
    tsum1 += __shfl_xor(tsum1, 16); tsum1 += __shfl_xor(tsum1, 32);
    float cw = ((lane < 16) ? tsum0 : tsum1) + g_bc2[0];

    // lanes 0..31 hold edges 0..31; mask the duplicate upper half
    float en = (lane < 32) ? 1.f : 0.f;
    float cx = en * cw * rx, cy = en * cw * ry, cz = en * cw * rz;
    #pragma unroll
    for (int off = 1; off <= 32; off <<= 1){
        cx += __shfl_xor(cx, off);
        cy += __shfl_xor(cy, off);
        cz += __shfl_xor(cz, off);
    }
    if (lane == 0){
        size_t base = (size_t)NODES * DIM + (size_t)gnode * 3;
        if (*flagp){
            float* o = (float*)dout;
            o[base+0] = cx + qx; o[base+1] = cy + qy; o[base+2] = cz + qz;
        } else {
            bf16* o = (bf16*)dout;
            o[base+0] = f2b(cx + qx); o[base+1] = f2b(cy + qy); o[base+2] = f2b(cz + qz);
        }
    }
}

// ---------------------------------------------------------------- K4: node MLP (writes d_out directly)
__global__ __launch_bounds__(256) void node_kernel(
        const float* __restrict__ feats, const float* __restrict__ m_i,
        const float* __restrict__ Wn1,   const float* __restrict__ bn1,
        const float* __restrict__ Wn2,   const float* __restrict__ bn2,
        void* __restrict__ dout,         const int* __restrict__ flagp){
    __shared__ float X[8][144];
    __shared__ float Hs[8][256];
    int t = threadIdx.x;
    int g0 = blockIdx.x << 3;

    for (int e = t; e < 8 * DIM; e += 256){
        int nd = e >> 7, c = e & 127;
        X[nd][c] = feats[(size_t)(g0 + nd) * DIM + c];
    }
    if (t < 128){
        int nd = t >> 4, c = t & 15;
        X[nd][DIM + c] = m_i[(size_t)(g0 + nd) * MD + c];
    }
    __syncthreads();

    float acc[8] = {};
    for (int r = 0; r < 144; ++r){
        float w = Wn1[(size_t)r * 256 + t];
        #pragma unroll
        for (int nd = 0; nd < 8; ++nd) acc[nd] += X[nd][r] * w;
    }
    float bb = bn1[t];
    #pragma unroll
    for (int nd = 0; nd < 8; ++nd) Hs[nd][t] = silu_f(acc[nd] + bb);
    __syncthreads();

    int c = t & 127, g = t >> 7;
    float a2[4] = {};
    for (int r = 0; r < 256; ++r){
        float w = Wn2[(size_t)r * DIM + c];
        #pragma unroll
        for (int u = 0; u < 4; ++u) a2[u] += Hs[g*4 + u][r] * w;
    }
    float b2v = bn2[c];
    int fl = *flagp;
    #pragma unroll
    for (int u = 0; u < 4; ++u){
        int nd = g*4 + u;
        float v = a2[u] + b2v + X[nd][c];
        size_t off2 = (size_t)(g0 + nd) * DIM + c;
        if (fl) ((float*)dout)[off2] = v;
        else    ((bf16*)dout)[off2]  = f2b(v);
    }
}

// ---------------------------------------------------------------- launch
extern "C" void kernel_launch(void* const* d_in, const int* in_sizes, int n_in,
                              void* d_out, int out_size, void* d_ws, size_t ws_size,
                              hipStream_t stream){
    char* ws = (char*)d_ws;
    size_t off = 0;
    auto alloc = [&](size_t bytes) -> char* {
        off = (off + 511) & ~(size_t)511;
        char* p = ws + off;
        off += bytes;
        return p;
    };

    int* flags = (int*)alloc(14 * 4);

    ConvTab tab;
    int total = 0;
    for (int i = 0; i < 14; ++i){ tab.prefix[i] = total; total += in_sizes[i]; }
    tab.prefix[14] = total;
    float* convBase = (float*)alloc((size_t)total * 4);
    int doff = 0;
    for (int i = 0; i < 14; ++i){
        tab.src[i] = d_in[i];
        tab.dstoff[i] = doff;
        doff += in_sizes[i];
    }

    unsigned short* gwimg = (unsigned short*)alloc((size_t)WIMG_SH * 2);
    unsigned short* We1T  = (unsigned short*)alloc((size_t)1088 * 128 * 2);
    unsigned short* fBF   = (unsigned short*)alloc((size_t)NODES * DIM * 2);
    int*   idx    = (int*)  alloc((size_t)NODES * KNNK * 4);
    unsigned short* P = (unsigned short*) alloc((size_t)NODES * PROW * 2);  // both batches, 17.8 MB
    float* mi     = (float*)alloc((size_t)NODES * MD * 4);

    Ptrs ps;
    for (int i = 0; i < 14; ++i){ ps.p[i] = d_in[i]; ps.n[i] = in_sizes[i]; }
    detect_kernel<<<14, 256, 0, stream>>>(ps, flags);
    convert_all<<<(total + 255) / 256, 256, 0, stream>>>(tab, flags, convBase);

    const float* feats = convBase + tab.dstoff[0];
    const float* coors = convBase + tab.dstoff[1];
    const float* We1 = convBase + tab.dstoff[2],  * be1 = convBase + tab.dstoff[3];
    const float* We2 = convBase + tab.dstoff[4],  * be2 = convBase + tab.dstoff[5];
    const float* Wc1 = convBase + tab.dstoff[6],  * bc1 = convBase + tab.dstoff[7];
    const float* Wc2 = convBase + tab.dstoff[8],  * bc2 = convBase + tab.dstoff[9];
    const float* Wn1 = convBase + tab.dstoff[10], * bn1 = convBase + tab.dstoff[11];
    const float* Wn2 = convBase + tab.dstoff[12], * bn2 = convBase + tab.dstoff[13];

    prep_kernel<<<(172032 + NODES * DIM) / 256, 256, 0, stream>>>(
        We1, We2, Wc1, be2, bc1, Wc2, bc2, feats, gwimg, We1T, fBF);
    knn_kernel<<<NODES/8, 512, 0, stream>>>(coors, idx);
    p_gemm<<<dim3(64, 34), 256, 0, stream>>>(fBF, We1T, be1, P);
    edge_kernel<<<NODES/8, 512, 0, stream>>>(coors, idx, gwimg, P, mi,
                                             d_out, flags + 0);
    node_kernel<<<1024, 256, 0, stream>>>(feats, mi, Wn1, bn1, Wn2, bn2,
                                          d_out, flags + 0);
}

// Round 15
// 248.813 us; speedup vs baseline: 1.7095x; 1.7095x over previous
//
#include <hip/hip_runtime.h>
#include <hip/hip_bf16.h>
#include <stdint.h>

typedef __hip_bfloat16 bf16;

using sh8    = __attribute__((ext_vector_type(8)))  short;
using sh4    = __attribute__((ext_vector_type(4)))  short;
using us4    = __attribute__((ext_vector_type(4)))  unsigned short;
using f32x16 = __attribute__((ext_vector_type(16))) float;
using fx4    = __attribute__((ext_vector_type(4)))  float;

#define NN    4096
#define NODES 8192
#define DIM   128
#define MD    16
#define KNNK  32
#define H1N   530
#define CPAD  544      // H1N padded to 17*32
#define PROW  1088     // [Pi 544 | Pj 544] per node, bf16

// weight-image offsets (in shorts)
#define OFF_W1AB 0      // [2][544][8]: half0 = W1f rows f0..7; half1 = [W1f8,0..0]
#define OFF_WE2A 8704   // [o][c] s=552  8832
#define OFF_WC1A 17536  // [u][k] s=32   2048
#define OFF_BE2  19584  // fp32[16]        32
#define OFF_BC1  19616  // fp32[64]       128
#define OFF_WC2  19744  // fp32[64]       128
#define OFF_BC2  19872  // fp32[4]          8
#define WIMG_SH  19880

__device__ __forceinline__ float b2f(bf16 x){ return __bfloat162float(x); }
__device__ __forceinline__ bf16  f2b(float x){ return __float2bfloat16(x); }
// fast silu: v_rcp_f32 (~1 ulp) instead of IEEE division
__device__ __forceinline__ float silu_f(float x){
    return x * __builtin_amdgcn_rcpf(1.f + __expf(-x));
}

__device__ __forceinline__ unsigned short f2us(float f){
    unsigned x = __float_as_uint(f);
    unsigned r = x + 0x7FFFu + ((x >> 16) & 1u);
    return (unsigned short)(r >> 16);
}
__device__ __forceinline__ float us2f(unsigned short u){
    return __uint_as_float(((unsigned)u) << 16);
}
// packed fp32x2 -> bf16x2 (v_cvt_pk_bf16_f32 on gfx950); low short = a
__device__ __forceinline__ unsigned pkbf(float a, float b){
    __hip_bfloat162 v = __float22bfloat162_rn(make_float2(a, b));
    return *(unsigned*)&v;
}

// ---------------------------------------------------------------- K0: dtype detect
struct Ptrs { const void* p[14]; int n[14]; };

__global__ __launch_bounds__(256) void detect_kernel(Ptrs ps, int* flags){
    int tn = blockIdx.x;
    const bf16* s = (const bf16*)ps.p[tn];
    int n = ps.n[tn]; if (n > 8192) n = 8192;
    int bad = 0;
    for (int i = threadIdx.x; i < n; i += 256){
        float v = b2f(s[i]);
        if (!(fabsf(v) <= 64.f)) bad = 1;   // catches NaN/Inf too
    }
    __shared__ int sbad;
    if (threadIdx.x == 0) sbad = 0;
    __syncthreads();
    if (bad) atomicOr(&sbad, 1);
    __syncthreads();
    if (threadIdx.x == 0) flags[tn] = sbad;   // 1 = fp32, 0 = bf16
}

// ---------------------------------------------------------------- K0b: fused convert
struct ConvTab {
    const void* src[14];
    int dstoff[14];
    int prefix[15];
};

__global__ __launch_bounds__(256) void convert_all(ConvTab tab,
                                                   const int* __restrict__ flags,
                                                   float* __restrict__ base){
    int gid = blockIdx.x * 256 + threadIdx.x;
    if (gid >= tab.prefix[14]) return;
    int tn = 0;
    #pragma unroll
    for (int k = 1; k < 14; ++k)
        if (gid >= tab.prefix[k]) tn = k;
    int local = gid - tab.prefix[tn];
    int f = flags[tn];
    float v = f ? ((const float*)tab.src[tn])[local]
                : b2f(((const bf16*)tab.src[tn])[local]);
    base[tab.dstoff[tn] + local] = v;
}

// ---------------------------------------------------------------- K0c: weight prep
__global__ __launch_bounds__(256) void prep_kernel(
        const float* __restrict__ We1, const float* __restrict__ We2,
        const float* __restrict__ Wc1, const float* __restrict__ be2,
        const float* __restrict__ bc1, const float* __restrict__ Wc2,
        const float* __restrict__ bc2, const float* __restrict__ feats,
        unsigned short* __restrict__ gwimg,
        unsigned short* __restrict__ We1T,
        unsigned short* __restrict__ fBF){
    int gid = blockIdx.x * 256 + threadIdx.x;
    if (gid < 4352){                         // W1AB half0: [c][f0..7]
        int c = gid >> 3, f = gid & 7;
        gwimg[OFF_W1AB + gid] = (c < H1N) ? f2us(We1[(size_t)(256 + f) * H1N + c]) : 0;
    } else if (gid < 8704){                  // W1AB half1: [c][W1f8,0,...]
        int e = gid - 4352; int c = e >> 3, jj = e & 7;
        gwimg[OFF_W1AB + 4352 + e] =
            (jj == 0 && c < H1N) ? f2us(We1[(size_t)264 * H1N + c]) : 0;
    } else if (gid < 17536){                 // We2^T s=552
        int e = gid - 8704; int o = e / 552, c = e - o * 552;
        gwimg[OFF_WE2A + e] = (c < H1N) ? f2us(We2[(size_t)c * 16 + o]) : 0;
    } else if (gid < 19584){                 // Wc1^T s=32
        int e = gid - 17536; int u = e >> 5, k = e & 31;
        gwimg[OFF_WC1A + e] = (k < 16) ? f2us(Wc1[(size_t)k * 64 + u]) : 0;
    } else if (gid < 19600){
        ((float*)(gwimg + OFF_BE2))[gid - 19584] = be2[gid - 19584];
    } else if (gid < 19664){
        ((float*)(gwimg + OFF_BC1))[gid - 19600] = bc1[gid - 19600];
    } else if (gid < 19728){
        ((float*)(gwimg + OFF_WC2))[gid - 19664] = Wc2[gid - 19664];
    } else if (gid < 19732){
        int z = gid - 19728;
        ((float*)(gwimg + OFF_BC2))[z] = (z == 0) ? bc2[0] : 0.f;
    } else if (gid >= 32768 && gid < 32768 + 1088 * 128){
        int e = gid - 32768; int n = e >> 7, k = e & 127;
        float v;
        if (n < CPAD) v = (n < H1N) ? We1[(size_t)k * H1N + n] : 0.f;
        else { int n2 = n - CPAD; v = (n2 < H1N) ? We1[(size_t)(128 + k) * H1N + n2] : 0.f; }
        We1T[e] = f2us(v);
    } else if (gid >= 172032 && gid < 172032 + NODES * DIM){
        int e = gid - 172032;
        fBF[e] = f2us(feats[e]);
    }
}

// ---------------------------------------------------------------- K1: KNN — wave-autonomous radix select
// One WAVE per node, zero __syncthreads. NO register caches (R14's bkp[32]/
// c16[16] caches spilled 474 MB of scratch under the (512,6) budget) —
// pass 2 recomputes distances instead (~4 us chip-wide, far cheaper than
// spilling). Set identical to jax.lax.top_k(-d, 32).
__global__ __launch_bounds__(512, 6) void knn_kernel(const float* __restrict__ coors,
                                                     int* __restrict__ idx_out){
    __shared__ unsigned hist[8][1024];              // 32 KB, wave-private
    __shared__ unsigned long long blist[8][64];     //  4 KB, wave-private
    __shared__ int cntO[8], cntB[8];

    int t = threadIdx.x, lane = t & 63, wid = t >> 6;
    int node = (blockIdx.x << 3) + wid;
    int b = node >> 12, i = node & (NN - 1);
    const float* cb = coors + (size_t)b * NN * 3;

    float qx = cb[i*3+0], qy = cb[i*3+1], qz = cb[i*3+2];

    unsigned* h = &hist[wid][0];
    {   // zero private hist: 4 x uint4 per lane (1024 bins)
        uint4* hz = (uint4*)h;
        uint4 z = make_uint4(0,0,0,0);
        #pragma unroll
        for (int zl = 0; zl < 4; ++zl) hz[zl * 64 + lane] = z;
    }
    if (lane == 0){ cntO[wid] = 0; cntB[wid] = 0; }
    asm volatile("" ::: "memory");

    // pass 1: distances -> bucket -> histogram (nothing cached)
    #pragma unroll 4
    for (int s = 0; s < 64; ++s){
        int j = (s << 6) + lane;
        float dx = qx - cb[j*3+0];
        float dy = qy - cb[j*3+1];
        float dz = qz - cb[j*3+2];
        float d  = dx*dx + dy*dy + dz*dz;
        float d2 = d * d;
        atomicAdd(&h[__float_as_uint(d2 * d2) >> 22], 1u);
    }
    asm volatile("s_waitcnt lgkmcnt(0)" ::: "memory");

    // intra-wave scan: lane owns bins [lane*16, lane*16+16) (read transiently)
    unsigned S = 0;
    {
        uint4* hz = (uint4*)h;
        #pragma unroll
        for (int g = 0; g < 4; ++g){
            uint4 v = hz[lane * 4 + g];
            S += v.x + v.y + v.z + v.w;
        }
    }
    unsigned scan = S;
    #pragma unroll
    for (int off = 1; off < 64; off <<= 1){
        unsigned nv = __shfl_up(scan, off);
        if (lane >= off) scan += nv;
    }
    unsigned excl = scan - S;
    unsigned long long own = __ballot(excl < KNNK && excl + S >= KNNK);
    int src = __ffsll((unsigned long long)own) - 1;
    unsigned run = excl, Bloc = 0, below_l = 0;
    #pragma unroll
    for (int r = 0; r < 16; ++r){
        unsigned c = h[lane * 16 + r];
        if (run < KNNK && run + c >= KNNK){ Bloc = lane * 16 + r; below_l = run; }
        run += c;
    }
    unsigned B    = __shfl(Bloc, src);
    unsigned below= __shfl(below_l, src);
    unsigned need = KNNK - below;

    // pass 2: recompute, emit strictly-below, push boundary
    int* co = &cntO[wid];
    int* cbn = &cntB[wid];
    unsigned long long* bl = &blist[wid][0];
    #pragma unroll 4
    for (int s = 0; s < 64; ++s){
        int j = (s << 6) + lane;
        float dx = qx - cb[j*3+0];
        float dy = qy - cb[j*3+1];
        float dz = qz - cb[j*3+2];
        float d  = dx*dx + dy*dy + dz*dz;
        float d2 = d * d;
        unsigned bk = __float_as_uint(d2 * d2) >> 22;
        if (bk < B){
            int pos = atomicAdd(co, 1);
            idx_out[(size_t)node * KNNK + pos] = j;
        } else if (bk == B){
            unsigned long long mk = ((unsigned long long)__float_as_uint(d) << 32)
                                    | (unsigned)j;
            int p = atomicAdd(cbn, 1);
            if (p < 64) bl[p] = mk;
        }
    }
    asm volatile("s_waitcnt lgkmcnt(0) vmcnt(0)" ::: "memory");
    int nb = *cbn;   // same-wave LDS in-order

    if (nb <= 64){
        unsigned long long e = (lane < nb) ? bl[lane] : ~0ull;
        for (unsigned r = 0; r < need; ++r){
            unsigned long long m = e;
            #pragma unroll
            for (int off = 32; off > 0; off >>= 1){
                unsigned long long o = __shfl_xor(m, off);
                if (o < m) m = o;
            }
            if (lane == 0)
                idx_out[(size_t)node * KNNK + below + r] = (int)(unsigned)(m & 0xffffffffull);
            if (e == m) e = ~0ull;
        }
    } else {
        // ~never: boundary bin overflowed the list — exact full-rescan selection
        unsigned long long lastk = 0;
        for (unsigned r = 0; r < need; ++r){
            unsigned long long lmin = ~0ull;
            for (int s = 0; s < 64; ++s){
                int j = (s << 6) + lane;
                float dx = qx - cb[j*3+0];
                float dy = qy - cb[j*3+1];
                float dz = qz - cb[j*3+2];
                float d  = dx*dx + dy*dy + dz*dz;
                float d2 = d * d;
                if ((__float_as_uint(d2 * d2) >> 22) == B){
                    unsigned long long mk = (((unsigned long long)__float_as_uint(d) << 32)
                                             | (unsigned)j) + 1ull;
                    if (mk > lastk && mk < lmin) lmin = mk;
                }
            }
            #pragma unroll
            for (int off = 32; off > 0; off >>= 1){
                unsigned long long o = __shfl_xor(lmin, off);
                if (o < lmin) lmin = o;
            }
            if (lane == 0)
                idx_out[(size_t)node * KNNK + below + r] =
                    (int)(unsigned)((lmin - 1ull) & 0xffffffffull);
            lastk = lmin;
        }
    }
}

// ---------------------------------------------------------------- K2: P-GEMM (MFMA, both batches)
__global__ __launch_bounds__(256) void p_gemm(const unsigned short* __restrict__ fBF,
                                              const unsigned short* __restrict__ We1T,
                                              const float* __restrict__ be1,
                                              unsigned short* __restrict__ P){
    int t = threadIdx.x, lane = t & 63, wid = t >> 6;
    int e31 = lane & 31, hi = lane >> 5;
    int mW = (blockIdx.x << 7) + (wid << 5);
    int n0 = blockIdx.y << 5;

    const unsigned short* Arow = fBF  + (size_t)(mW + e31) * DIM + hi * 8;
    const unsigned short* Brow = We1T + (size_t)(n0 + e31) * DIM + hi * 8;

    f32x16 acc = {0.f,0.f,0.f,0.f,0.f,0.f,0.f,0.f,0.f,0.f,0.f,0.f,0.f,0.f,0.f,0.f};
    #pragma unroll
    for (int kc = 0; kc < 8; ++kc){
        sh8 a  = *(const sh8*)(Arow + kc * 16);
        sh8 bv = *(const sh8*)(Brow + kc * 16);
        acc = __builtin_amdgcn_mfma_f32_32x32x16_bf16(a, bv, acc, 0, 0, 0);
    }
    int n = n0 + e31;
    float beadd = 0.f;
    if (n < CPAD) beadd = (n < H1N) ? be1[n] : 0.f;   // fold be1 into Pi half
    #pragma unroll
    for (int g = 0; g < 4; ++g)
        #pragma unroll
        for (int r = 0; r < 4; ++r){
            int m = mW + 8*g + 4*hi + r;
            P[(size_t)m * PROW + n] = f2us(acc[4*g + r] + beadd);
        }
}

// ---------------------------------------------------------------- K3: edges (MFMA, 8 nodes/block)
// 512 threads = 8 waves, 1 wave/node. Pj stream coalesced via wave-local LDS
// stage (2 whole-line loads/lane per chunk). See R13 notes.
__global__ __launch_bounds__(512, 6) void edge_kernel(
        const float* __restrict__ coors, const int* __restrict__ idx,
        const unsigned short* __restrict__ gw,
        const unsigned short* __restrict__ P,
        float* __restrict__ mi_out, void* __restrict__ dout,
        const int* __restrict__ flagp){
    __shared__ __align__(16) unsigned short sWe2[16 * 552];   // 17.7 KB
    __shared__ __align__(16) unsigned short trans[8][1280];   // 20.5 KB (wave-local)

    int t = threadIdx.x, lane = t & 63, wid = t >> 6;
    int gnode = (blockIdx.x << 3) + wid;
    int b = gnode >> 12;

    {   // stage We2^T (coalesced float4 copy), one barrier
        const float4* s1 = (const float4*)(gw + OFF_WE2A);
        float4* d1 = (float4*)sWe2;
        for (int e = t; e < 1104; e += 512) d1[e] = s1[e];
    }

    const float* cb = coors + (size_t)b * NN * 3;
    int i = gnode & (NN - 1);
    float qx = cb[i*3+0], qy = cb[i*3+1], qz = cb[i*3+2];

    int e31 = lane & 31, hi = lane >> 5;
    int e15 = lane & 15, q  = lane >> 4;

    // every lane owns edge e31 (lanes 32..63 duplicate 0..31)
    int jme = idx[(size_t)gnode * KNNK + e31];
    float rx = qx - cb[jme*3+0];
    float ry = qy - cb[jme*3+1];
    float rz = qz - cb[jme*3+2];
    float d = rx*rx + ry*ry + rz*rz;

    unsigned frb[9];
    frb[0] = f2us(sinf(d));         frb[1] = f2us(sinf(d * 0.5f));
    frb[2] = f2us(sinf(d * 0.25f)); frb[3] = f2us(sinf(d * 0.125f));
    frb[4] = f2us(cosf(d));         frb[5] = f2us(cosf(d * 0.5f));
    frb[6] = f2us(cosf(d * 0.25f)); frb[7] = f2us(cosf(d * 0.125f));
    frb[8] = f2us(d);

    // hi=0: B[k=0..7][e] = fourier; hi=1: B[8][e]=d, B[9][e]=1.0 (Pi slot)
    sh8 bfragC;
    #pragma unroll
    for (int j = 0; j < 8; ++j)
        bfragC[j] = (hi == 0) ? (short)frb[j]
                  : (short)((j == 0) ? frb[8] : (j == 1) ? 0x3F80u : 0u);

    // coalesced Pj staging: lane covers row (lane>>2) and row 16+(lane>>2),
    // 16 B each at quarter (lane&3). Whole 64 B lines per row.
    int nbase = gnode & ~(NN - 1);
    int j0 = __shfl(jme, lane >> 2);
    int j1 = __shfl(jme, 16 + (lane >> 2));
    const unsigned short* Pst0 = P + (size_t)(nbase + j0) * PROW + CPAD + (lane & 3) * 8;
    const unsigned short* Pst1 = P + (size_t)(nbase + j1) * PROW + CPAD + (lane & 3) * 8;
    const unsigned short* Pirow = P + (size_t)gnode * PROW;

    unsigned short* stg = &trans[wid][0];                 // stride 40 shorts
    unsigned short* sw0 = stg + (lane >> 2) * 40 + (lane & 3) * 8;
    unsigned short* sw1 = stg + (16 + (lane >> 2)) * 40 + (lane & 3) * 8;

    const float* g_be2 = (const float*)(gw + OFF_BE2);
    const float* g_bc1 = (const float*)(gw + OFF_BC1);
    const float* g_wc2 = (const float*)(gw + OFF_WC2);
    const float* g_bc2 = (const float*)(gw + OFF_BC2);

    fx4 accD0 = {0.f,0.f,0.f,0.f};
    fx4 accD1 = {0.f,0.f,0.f,0.f};

    __syncthreads();   // staged weights visible

    for (int ch = 0; ch < 17; ++ch){
        int c0 = ch * 32;
        // coalesced Pj stage: 2 x 16 B/lane -> 32 rows x 64 B
        sh8 g0v = *(const sh8*)(Pst0 + c0);
        sh8 g1v = *(const sh8*)(Pst1 + c0);
        unsigned short piS = Pirow[c0 + e31];
        sh8 afrag = *(const sh8*)(gw + OFF_W1AB + (size_t)(hi * 544 + c0 + e31) * 8);
        afrag[1] = hi ? (short)piS : afrag[1];            // Pi into k=9 slot

        *(sh8*)sw0 = g0v;                                  // ds_write_b128 x2
        *(sh8*)sw1 = g1v;
        asm volatile("s_waitcnt lgkmcnt(0)" ::: "memory"); // stage visible (intra-wave)

        f32x16 cc;   // C-init = Pj (from LDS stage); Pi comes through the MFMA
        #pragma unroll
        for (int g = 0; g < 4; ++g){
            us4 pj = *(const us4*)(stg + e31 * 40 + 8*g + 4*hi);
            cc[4*g+0] = us2f(pj.x);
            cc[4*g+1] = us2f(pj.y);
            cc[4*g+2] = us2f(pj.z);
            cc[4*g+3] = us2f(pj.w);
        }
        f32x16 h = __builtin_amdgcn_mfma_f32_32x32x16_bf16(afrag, bfragC, cc, 0, 0, 0);

        // h1 -> bf16 into the SAME buffer (Pj values already consumed;
        // same-wave LDS ops process in order)
        #pragma unroll
        for (int g = 0; g < 4; ++g){
            unsigned lo = pkbf(silu_f(h[4*g+0]), silu_f(h[4*g+1]));
            unsigned hi2 = pkbf(silu_f(h[4*g+2]), silu_f(h[4*g+3]));
            *(uint2*)&stg[e31 * 40 + 8*g + 4*hi] = make_uint2(lo, hi2);
        }
        asm volatile("s_waitcnt lgkmcnt(0)" ::: "memory"); // intra-wave LDS RAW

        sh8 wa  = *(const sh8*)&sWe2[e15 * 552 + c0 + q * 8];
        sh8 bt0 = *(const sh8*)&stg[e15 * 40 + q * 8];
        sh8 bt1 = *(const sh8*)&stg[(16 + e15) * 40 + q * 8];
        accD0 = __builtin_amdgcn_mfma_f32_16x16x32_bf16(wa, bt0, accD0, 0, 0, 0);
        accD1 = __builtin_amdgcn_mfma_f32_16x16x32_bf16(wa, bt1, accD1, 0, 0, 0);
    }

    // ---- m = silu(OUT2 + be2); sM (aliases trans head); m_i butterfly ----
    fx4 be2q = *(const fx4*)&g_be2[q * 4];
    float msum[4];
    float mv0[4], mv1[4];
    #pragma unroll
    for (int r = 0; r < 4; ++r){
        mv0[r] = silu_f(accD0[r] + be2q[r]);
        mv1[r] = silu_f(accD1[r] + be2q[r]);
        msum[r] = mv0[r] + mv1[r];
    }
    *(uint2*)&stg[e15 * 16 + q * 4] =
        make_uint2(pkbf(mv0[0], mv0[1]), pkbf(mv0[2], mv0[3]));
    *(uint2*)&stg[(16 + e15) * 16 + q * 4] =
        make_uint2(pkbf(mv1[0], mv1[1]), pkbf(mv1[2], mv1[3]));
    #pragma unroll
    for (int r = 0; r < 4; ++r){
        msum[r] += __shfl_xor(msum[r], 1);
        msum[r] += __shfl_xor(msum[r], 2);
        msum[r] += __shfl_xor(msum[r], 4);
        msum[r] += __shfl_xor(msum[r], 8);
    }
    if (e15 == 0){
        fx4 mv = { msum[0], msum[1], msum[2], msum[3] };
        *(fx4*)(mi_out + (size_t)gnode * MD + q * 4) = mv;
    }
    asm volatile("s_waitcnt lgkmcnt(0)" ::: "memory");

    // ---- phase E: coors MLP ----
    float tsum0 = 0.f, tsum1 = 0.f;
    #pragma unroll
    for (int ut = 0; ut < 4; ++ut){
        sh8 wa3 = *(const sh8*)(gw + OFF_WC1A + (size_t)(ut * 16 + e15) * 32 + q * 8);
        sh8 b0  = (q < 2) ? *(const sh8*)&stg[e15 * 16 + q * 8]        : (sh8)0;
        sh8 b1  = (q < 2) ? *(const sh8*)&stg[(16 + e15) * 16 + q * 8] : (sh8)0;
        fx4 a0 = {0.f,0.f,0.f,0.f};
        fx4 a1 = {0.f,0.f,0.f,0.f};
        a0 = __builtin_amdgcn_mfma_f32_16x16x32_bf16(wa3, b0, a0, 0, 0, 0);
        a1 = __builtin_amdgcn_mfma_f32_16x16x32_bf16(wa3, b1, a1, 0, 0, 0);
        fx4 bc1q = *(const fx4*)&g_bc1[ut * 16 + q * 4];
        fx4 wcq  = *(const fx4*)&g_wc2[ut * 16 + q * 4];
        #pragma unroll
        for (int r = 0; r < 4; ++r){
            tsum0 += silu_f(a0[r] + bc1q[r]) * wcq[r];
            tsum1 += silu_f(a1[r] + bc1q[r]) * wcq[r];
        }
    }
    tsum0 += __shfl_xor(tsum0, 16); tsum0 += __shfl_xor(tsum0, 32);
    tsum1 += __shfl_xor(tsum1, 16); tsum1 += __shfl_xor(tsum1, 32);
    float cw = ((lane < 16) ? tsum0 : tsum1) + g_bc2[0];

    // lanes 0..31 hold edges 0..31; mask the duplicate upper half
    float en = (lane < 32) ? 1.f : 0.f;
    float cx = en * cw * rx, cy = en * cw * ry, cz = en * cw * rz;
    #pragma unroll
    for (int off = 1; off <= 32; off <<= 1){
        cx += __shfl_xor(cx, off);
        cy += __shfl_xor(cy, off);
        cz += __shfl_xor(cz, off);
    }
    if (lane == 0){
        size_t base = (size_t)NODES * DIM + (size_t)gnode * 3;
        if (*flagp){
            float* o = (float*)dout;
            o[base+0] = cx + qx; o[base+1] = cy + qy; o[base+2] = cz + qz;
        } else {
            bf16* o = (bf16*)dout;
            o[base+0] = f2b(cx + qx); o[base+1] = f2b(cy + qy); o[base+2] = f2b(cz + qz);
        }
    }
}

// ---------------------------------------------------------------- K4: node MLP (writes d_out directly)
__global__ __launch_bounds__(256) void node_kernel(
        const float* __restrict__ feats, const float* __restrict__ m_i,
        const float* __restrict__ Wn1,   const float* __restrict__ bn1,
        const float* __restrict__ Wn2,   const float* __restrict__ bn2,
        void* __restrict__ dout,         const int* __restrict__ flagp){
    __shared__ float X[8][144];
    __shared__ float Hs[8][256];
    int t = threadIdx.x;
    int g0 = blockIdx.x << 3;

    for (int e = t; e < 8 * DIM; e += 256){
        int nd = e >> 7, c = e & 127;
        X[nd][c] = feats[(size_t)(g0 + nd) * DIM + c];
    }
    if (t < 128){
        int nd = t >> 4, c = t & 15;
        X[nd][DIM + c] = m_i[(size_t)(g0 + nd) * MD + c];
    }
    __syncthreads();

    float acc[8] = {};
    for (int r = 0; r < 144; ++r){
        float w = Wn1[(size_t)r * 256 + t];
        #pragma unroll
        for (int nd = 0; nd < 8; ++nd) acc[nd] += X[nd][r] * w;
    }
    float bb = bn1[t];
    #pragma unroll
    for (int nd = 0; nd < 8; ++nd) Hs[nd][t] = silu_f(acc[nd] + bb);
    __syncthreads();

    int c = t & 127, g = t >> 7;
    float a2[4] = {};
    for (int r = 0; r < 256; ++r){
        float w = Wn2[(size_t)r * DIM + c];
        #pragma unroll
        for (int u = 0; u < 4; ++u) a2[u] += Hs[g*4 + u][r] * w;
    }
    float b2v = bn2[c];
    int fl = *flagp;
    #pragma unroll
    for (int u = 0; u < 4; ++u){
        int nd = g*4 + u;
        float v = a2[u] + b2v + X[nd][c];
        size_t off2 = (size_t)(g0 + nd) * DIM + c;
        if (fl) ((float*)dout)[off2] = v;
        else    ((bf16*)dout)[off2]  = f2b(v);
    }
}

// ---------------------------------------------------------------- launch
extern "C" void kernel_launch(void* const* d_in, const int* in_sizes, int n_in,
                              void* d_out, int out_size, void* d_ws, size_t ws_size,
                              hipStream_t stream){
    char* ws = (char*)d_ws;
    size_t off = 0;
    auto alloc = [&](size_t bytes) -> char* {
        off = (off + 511) & ~(size_t)511;
        char* p = ws + off;
        off += bytes;
        return p;
    };

    int* flags = (int*)alloc(14 * 4);

    ConvTab tab;
    int total = 0;
    for (int i = 0; i < 14; ++i){ tab.prefix[i] = total; total += in_sizes[i]; }
    tab.prefix[14] = total;
    float* convBase = (float*)alloc((size_t)total * 4);
    int doff = 0;
    for (int i = 0; i < 14; ++i){
        tab.src[i] = d_in[i];
        tab.dstoff[i] = doff;
        doff += in_sizes[i];
    }

    unsigned short* gwimg = (unsigned short*)alloc((size_t)WIMG_SH * 2);
    unsigned short* We1T  = (unsigned short*)alloc((size_t)1088 * 128 * 2);
    unsigned short* fBF   = (unsigned short*)alloc((size_t)NODES * DIM * 2);
    int*   idx    = (int*)  alloc((size_t)NODES * KNNK * 4);
    unsigned short* P = (unsigned short*) alloc((size_t)NODES * PROW * 2);  // both batches, 17.8 MB
    float* mi     = (float*)alloc((size_t)NODES * MD * 4);

    Ptrs ps;
    for (int i = 0; i < 14; ++i){ ps.p[i] = d_in[i]; ps.n[i] = in_sizes[i]; }
    detect_kernel<<<14, 256, 0, stream>>>(ps, flags);
    convert_all<<<(total + 255) / 256, 256, 0, stream>>>(tab, flags, convBase);

    const float* feats = convBase + tab.dstoff[0];
    const float* coors = convBase + tab.dstoff[1];
    const float* We1 = convBase + tab.dstoff[2],  * be1 = convBase + tab.dstoff[3];
    const float* We2 = convBase + tab.dstoff[4],  * be2 = convBase + tab.dstoff[5];
    const float* Wc1 = convBase + tab.dstoff[6],  * bc1 = convBase + tab.dstoff[7];
    const float* Wc2 = convBase + tab.dstoff[8],  * bc2 = convBase + tab.dstoff[9];
    const float* Wn1 = convBase + tab.dstoff[10], * bn1 = convBase + tab.dstoff[11];
    const float* Wn2 = convBase + tab.dstoff[12], * bn2 = convBase + tab.dstoff[13];

    prep_kernel<<<(172032 + NODES * DIM) / 256, 256, 0, stream>>>(
        We1, We2, Wc1, be2, bc1, Wc2, bc2, feats, gwimg, We1T, fBF);
    knn_kernel<<<NODES/8, 512, 0, stream>>>(coors, idx);
    p_gemm<<<dim3(64, 34), 256, 0, stream>>>(fBF, We1T, be1, P);
    edge_kernel<<<NODES/8, 512, 0, stream>>>(coors, idx, gwimg, P, mi,
                                             d_out, flags + 0);
    node_kernel<<<1024, 256, 0, stream>>>(feats, mi, Wn1, bn1, Wn2, bn2,
                                          d_out, flags + 0);
}